// Round 15
// baseline (53.216 us; speedup 1.0000x reference)
//
#include <hip/hip_runtime.h>
#include <hip/hip_bf16.h>

#define LL 128
#define DD 256
#define PP 1024
#define TU_C 86400
#define TB_C 3600
#define NEGF -4294967296.0f   // float(-2**32+1) rounds to -2^32

// NOTE: parameter names must not collide with .x/.y/.z/.w member tokens
#define FMA4(ACC_, SS_, WW_) { (ACC_).x += (SS_)*(WW_).x; (ACC_).y += (SS_)*(WW_).y; (ACC_).z += (SS_)*(WW_).z; (ACC_).w += (SS_)*(WW_).w; }
#define ADD4(ACC_, WW_) { (ACC_).x += (WW_).x; (ACC_).y += (WW_).y; (ACC_).z += (WW_).z; (ACC_).w += (WW_).w; }

__device__ __forceinline__ float wredSum(float v) {
#pragma unroll
  for (int o = 32; o; o >>= 1) v += __shfl_xor(v, o);
  return v;
}
__device__ __forceinline__ float wredMax(float v) {
#pragma unroll
  for (int o = 32; o; o >>= 1) v = fmaxf(v, __shfl_xor(v, o));
  return v;
}

// ---------------------------------------------------------------------------
// Kernel 1: QKV projections from UNTRANSPOSED weights (in-block LDS transpose,
// 32-e chunks) + folded transposes of wf1/wf2/wdec.
// grid 256 x 256 thr: bx<192 -> GEMM (mat x 8-row tile) + 1 transpose tile;
// bx in [192,256) -> 3 transpose tiles each. Tiles: wf1 0-63, wf2 64-127,
// wdec 128-383. K written TRANSPOSED per batch: KT[b][e][k].
// ---------------------------------------------------------------------------
__global__ __launch_bounds__(256) void k_qkv2(
    const float* __restrict__ wq, const float* __restrict__ wk,
    const float* __restrict__ wv, const float* __restrict__ wf1,
    const float* __restrict__ wf2, const float* __restrict__ wdec,
    const float* __restrict__ src,
    const float* __restrict__ bq, const float* __restrict__ bk,
    const float* __restrict__ bv,
    float* __restrict__ WT,
    float* __restrict__ Q, float* __restrict__ KT, float* __restrict__ V)
{
  const int bx = blockIdx.x;
  const int t = threadIdx.x;
  __shared__ float xs[8][DD];
  __shared__ float wlds[32][260];   // 32-e chunk, transposed; 260: 16B-aligned rows
  __shared__ float st[32][33];

  const int tx = t & 31, ty = t >> 5;
  auto do_tile = [&](int tile) {
    const float* sw; float* dst; int R, m;
    if (tile < 64)       { sw = wf1;  dst = WT + 196608; R = 256;  m = tile; }
    else if (tile < 128) { sw = wf2;  dst = WT + 262144; R = 256;  m = tile - 64; }
    else                 { sw = wdec; dst = WT + 327680; R = 1024; m = tile - 128; }
    const int sr = (m >> 3) * 32, sc0 = (m & 7) * 32;
    __syncthreads();
#pragma unroll
    for (int i = 0; i < 4; ++i)
      st[ty + 8 * i][tx] = sw[(sr + ty + 8 * i) * 256 + sc0 + tx];
    __syncthreads();
#pragma unroll
    for (int i = 0; i < 4; ++i)
      dst[(sc0 + ty + 8 * i) * R + sr + tx] = st[tx][ty + 8 * i];
  };

  if (bx >= 192) {
#pragma unroll
    for (int q = 0; q < 3; ++q) do_tile(192 + (bx - 192) * 3 + q);
    return;
  }
  // ---- GEMM path: out[r][col] = src[r][:] . w[col][:] + b[col] ----
  const int mat = bx >> 6;
  const int r0 = (bx & 63) * 8;
  const float* wm = (mat == 0) ? wq : (mat == 1) ? wk : wv;
  for (int i = t; i < 8 * DD; i += 256) xs[i >> 8][i & 255] = src[r0 * DD + i];
  do_tile(bx);   // barriers inside also make xs visible
  const int cg = t & 63, w = t >> 6;
  const int col4 = 4 * cg;
  const int rA = 2 * w, rB = rA + 1;
  float4 a0 = {0.f,0.f,0.f,0.f}, a1 = {0.f,0.f,0.f,0.f};
  for (int c = 0; c < 8; ++c) {
    const int e1 = c * 32;
    __syncthreads();          // wlds reads of prev chunk done
#pragma unroll
    for (int it = 0; it < 32; ++it) {
      const int idx = it * 256 + t;
      const int ccol = idx >> 5, eo = idx & 31;
      wlds[eo][ccol] = wm[ccol * 256 + e1 + eo];   // coalesced along e
    }
    __syncthreads();
#pragma unroll
    for (int eo = 0; eo < 32; ++eo) {
      const float4 w4 = *(const float4*)&wlds[eo][col4];
      FMA4(a0, xs[rA][e1 + eo], w4)
      FMA4(a1, xs[rB][e1 + eo], w4)
    }
  }
  const float* bi = (mat == 0) ? bq : (mat == 1) ? bk : bv;
  const float4 b4v = *(const float4*)(bi + col4);
  ADD4(a0, b4v) ADD4(a1, b4v)
  const int gA = r0 + rA, gB = r0 + rB;
  if (mat == 1) {
    const int bA = gA >> 7, kA = gA & 127;       // gA even -> gB same batch
    KT[bA * 32768 + (col4 + 0) * 128 + kA] = a0.x;
    KT[bA * 32768 + (col4 + 1) * 128 + kA] = a0.y;
    KT[bA * 32768 + (col4 + 2) * 128 + kA] = a0.z;
    KT[bA * 32768 + (col4 + 3) * 128 + kA] = a0.w;
    KT[bA * 32768 + (col4 + 0) * 128 + kA + 1] = a1.x;
    KT[bA * 32768 + (col4 + 1) * 128 + kA + 1] = a1.y;
    KT[bA * 32768 + (col4 + 2) * 128 + kA + 1] = a1.z;
    KT[bA * 32768 + (col4 + 3) * 128 + kA + 1] = a1.w;
  } else {
    float* o = (mat == 0) ? Q : V;
    *(float4*)(o + gA * DD + col4) = a0;
    *(float4*)(o + gB * DD + col4) = a1;
  }
}

// ---------------------------------------------------------------------------
// Kernel 2: FULLY FUSED attention + FFN. grid 256 = (b, 64 row-pairs),
// 512 thr = 8 waves. Online-softmax merge: ONE barrier publishes per-wave
// (max, sum-exp); combine via Z = z0*e^(m0-M) + z1*e^(m1-M).
// ---------------------------------------------------------------------------
__global__ __launch_bounds__(512) void k_attn(
    const float* __restrict__ Q, const float* __restrict__ KT,
    const float* __restrict__ Vm, const float* __restrict__ src,
    const float* __restrict__ hour_emb, const float* __restrict__ day_emb,
    const int* __restrict__ seq_lens, const int* __restrict__ ts_g,
    const float* __restrict__ g11, const float* __restrict__ b11,
    const float* __restrict__ wt1, const float* __restrict__ bf1,
    const float* __restrict__ wt2, const float* __restrict__ bf2,
    const float* __restrict__ g12, const float* __restrict__ b12,
    float* __restrict__ F)
{
  const int b = blockIdx.x >> 6;
  const int j0 = (blockIdx.x & 63) * 2;
  const int t = threadIdx.x, w = t >> 6, l = t & 63;
  const int col = 4 * l;
  __shared__ float qs[2][DD];
  __shared__ int   tsl[LL];
  __shared__ float qhd[2][34];
  __shared__ float whd[2][34];
  __shared__ float red[8];
  __shared__ float ss[2][LL];
  __shared__ float xs2[2][DD];
  __shared__ float hs2[2][DD];
  __shared__ float ps[8][2][DD];
  const int row0 = b * LL + j0;
  qs[t >> 8][t & 255] = Q[row0 * DD + t];    // 512 threads = 2x256
  if (t < LL) tsl[t] = ts_g[b * LL + t];
  if (t < 68) whd[t / 34][t % 34] = 0.f;
  __syncthreads();   // B1
  float kdot = 0.f;
  int krow = 0, kidx = 0;
  if (w < 4) {
    krow = w >> 1;
    kidx = ((w & 1) << 6) | l;
    const float* ktb = KT + b * 32768;
    float4 kd = {0.f,0.f,0.f,0.f};
#pragma unroll 8
    for (int e = 0; e < DD; e += 4) {
      const float4 q4 = *(const float4*)&qs[krow][e];
      const float* kp = ktb + e * LL + kidx;
      kd.x += q4.x * kp[0];
      kd.y += q4.y * kp[128];
      kd.z += q4.z * kp[256];
      kd.w += q4.w * kp[384];
    }
    kdot = (kd.x + kd.y) + (kd.z + kd.w);
  } else if (w < 6 && l < 34) {
    const int r = w - 4;
    const float* ep = (l < 26) ? (hour_emb + l * DD) : (day_emb + (l - 26) * DD);
    float4 ed = {0.f,0.f,0.f,0.f};
    for (int e = 0; e < DD; e += 4) {
      const float4 q4 = *(const float4*)&qs[r][e];
      const float4 e4 = *(const float4*)(ep + e);
      ed.x += q4.x * e4.x; ed.y += q4.y * e4.y;
      ed.z += q4.z * e4.z; ed.w += q4.w * e4.w;
    }
    qhd[r][l] = (ed.x + ed.y) + (ed.z + ed.w);
  }
  __syncthreads();   // B2 (qhd ready)
  const int len = seq_lens[b];
  float s = NEGF;
  int hidx = 0, didx = 0;
  float pv = 0.f, mw = 0.f;
  if (w < 4) {
    const int jrow = j0 + krow;
    if (kidx <= jrow && jrow < len) {
      const int df = tsl[jrow] - tsl[kidx];              // >=0 (sorted, k<=j)
      hidx = (jrow == b) ? 1 : ((df % TU_C) / TB_C + 2); // faithful j==b bug
      didx = min(df / TU_C + 1, 7);
      s = (kdot + qhd[krow][hidx] + qhd[krow][26 + didx]) * 0.0625f;
    }
    mw = wredMax(s);
    pv = expf(s - mw);               // all-NEG wave -> mw=NEG, pv=1
    const float zv = wredSum(pv);
    if (l == 0) { red[w] = mw; red[4 + w] = zv; }
  }
  __syncthreads();   // B3 (single softmax barrier)
  if (w < 4) {
    const float m0 = red[2 * krow], m1 = red[2 * krow + 1];
    const float M = fmaxf(m0, m1);
    const float Z = red[4 + 2 * krow] * expf(m0 - M)
                  + red[5 + 2 * krow] * expf(m1 - M);
    const float aw = pv * (expf(mw - M) / Z);   // all-NEG row -> 1/128
    ss[krow][kidx] = aw;
    atomicAdd(&whd[krow][hidx], aw);       // idx 0 -> zero emb row: harmless
    atomicAdd(&whd[krow][26 + didx], aw);
  }
  __syncthreads();   // B4 (ss/whd ready)
  // Phase 1: aw@V k-slice (16 k's per wave), both rows
  {
    float4 a0 = {0.f,0.f,0.f,0.f}, a1 = {0.f,0.f,0.f,0.f};
    const float* vb = Vm + b * LL * DD + col;
    const int k0 = 16 * w;
#pragma unroll
    for (int kk = 0; kk < 16; ++kk) {
      const int k = k0 + kk;
      const float4 v4 = *(const float4*)(vb + k * DD);
      FMA4(a0, ss[0][k], v4)
      FMA4(a1, ss[1][k], v4)
    }
    if (w == 0) {
#pragma unroll
      for (int i = 0; i < 26; ++i)
        FMA4(a0, whd[0][i], *(const float4*)(hour_emb + i * DD + col))
    } else if (w == 1) {
#pragma unroll
      for (int i = 0; i < 26; ++i)
        FMA4(a1, whd[1][i], *(const float4*)(hour_emb + i * DD + col))
    } else if (w == 2) {
#pragma unroll
      for (int i = 0; i < 8; ++i)
        FMA4(a0, whd[0][26 + i], *(const float4*)(day_emb + i * DD + col))
      const float4 s4 = *(const float4*)(src + row0 * DD + col);
      ADD4(a0, s4)
    } else if (w == 3) {
#pragma unroll
      for (int i = 0; i < 8; ++i)
        FMA4(a1, whd[1][26 + i], *(const float4*)(day_emb + i * DD + col))
      const float4 s4 = *(const float4*)(src + (row0 + 1) * DD + col);
      ADD4(a1, s4)
    }
    *(float4*)&ps[w][0][col] = a0;
    *(float4*)&ps[w][1][col] = a1;
  }
  __syncthreads();   // B5
  if (w < 2) {   // combine + LN1 (wave w = row w)
    float4 x = *(const float4*)&ps[0][w][col];
#pragma unroll
    for (int i = 1; i < 8; ++i) ADD4(x, (*(const float4*)&ps[i][w][col]))
    const float sm = wredSum(x.x + x.y + x.z + x.w);
    const float sq = wredSum(x.x*x.x + x.y*x.y + x.z*x.z + x.w*x.w);
    const float mean = sm * (1.f / DD);
    const float rstd = rsqrtf(sq * (1.f / DD) - mean * mean + 1e-5f);
    const float4 g4 = *(const float4*)(g11 + col);
    const float4 b4 = *(const float4*)(b11 + col);
    x.x = (x.x - mean) * rstd * g4.x + b4.x;
    x.y = (x.y - mean) * rstd * g4.y + b4.y;
    x.z = (x.z - mean) * rstd * g4.z + b4.z;
    x.w = (x.w - mean) * rstd * g4.w + b4.w;
    *(float4*)&xs2[w][col] = x;
  }
  __syncthreads();   // B6
  {   // FFN1 e-slice (32 e's per wave), both rows per weight read
    float4 a0 = {0.f,0.f,0.f,0.f}, a1 = {0.f,0.f,0.f,0.f};
    const int e0 = 32 * w;
#pragma unroll 8
    for (int ee = 0; ee < 32; ++ee) {
      const int e = e0 + ee;
      const float4 w4 = *(const float4*)(wt1 + e * DD + col);
      FMA4(a0, xs2[0][e], w4)
      FMA4(a1, xs2[1][e], w4)
    }
    *(float4*)&ps[w][0][col] = a0;
    *(float4*)&ps[w][1][col] = a1;
  }
  __syncthreads();   // B7
  if (w < 2) {   // combine + bias + relu
    float4 h = *(const float4*)(bf1 + col);
#pragma unroll
    for (int i = 0; i < 8; ++i) ADD4(h, (*(const float4*)&ps[i][w][col]))
    h.x = fmaxf(h.x, 0.f); h.y = fmaxf(h.y, 0.f);
    h.z = fmaxf(h.z, 0.f); h.w = fmaxf(h.w, 0.f);
    *(float4*)&hs2[w][col] = h;
  }
  __syncthreads();   // B8
  {   // FFN2 e-slice
    float4 a0 = {0.f,0.f,0.f,0.f}, a1 = {0.f,0.f,0.f,0.f};
    const int e0 = 32 * w;
#pragma unroll 8
    for (int ee = 0; ee < 32; ++ee) {
      const int e = e0 + ee;
      const float4 w4 = *(const float4*)(wt2 + e * DD + col);
      FMA4(a0, hs2[0][e], w4)
      FMA4(a1, hs2[1][e], w4)
    }
    *(float4*)&ps[w][0][col] = a0;
    *(float4*)&ps[w][1][col] = a1;
  }
  __syncthreads();   // B9
  if (w < 2) {   // combine + bias + residual + LN2 + store
    float4 o = *(const float4*)(bf2 + col);
#pragma unroll
    for (int i = 0; i < 8; ++i) ADD4(o, (*(const float4*)&ps[i][w][col]))
    const float4 xr = *(const float4*)&xs2[w][col];
    ADD4(o, xr)
    const float sm = wredSum(o.x + o.y + o.z + o.w);
    const float sq = wredSum(o.x*o.x + o.y*o.y + o.z*o.z + o.w*o.w);
    const float mean = sm * (1.f / DD);
    const float rstd = rsqrtf(sq * (1.f / DD) - mean * mean + 1e-5f);
    const float4 g4 = *(const float4*)(g12 + col);
    const float4 b4 = *(const float4*)(b12 + col);
    o.x = (o.x - mean) * rstd * g4.x + b4.x;
    o.y = (o.y - mean) * rstd * g4.y + b4.y;
    o.z = (o.z - mean) * rstd * g4.z + b4.z;
    o.w = (o.w - mean) * rstd * g4.w + b4.w;
    *(float4*)(F + (row0 + w) * DD + col) = o;
  }
}

// ---------------------------------------------------------------------------
// Kernel 3: FUSED prep + decoder GEMM. grid (4 col-tiles of 256, 64 row-tiles
// of 8) = 256 blocks, 256 thr = 4 waves. (round-12 proven structure)
// ---------------------------------------------------------------------------
__global__ __launch_bounds__(256) void k_decf(
    const float* __restrict__ F,
    const float* __restrict__ hour_emb, const float* __restrict__ day_emb,
    const int* __restrict__ seq_lens, const int* __restrict__ ts_g,
    const int* __restrict__ lts_g,
    const float* __restrict__ wtd, const float* __restrict__ bdec,
    float* __restrict__ out)
{
  const int c0 = blockIdx.x * 256;
  const int r0g = blockIdx.y * 8;
  const int b = r0g >> 7, j0 = r0g & 127;
  const int t = threadIdx.x, l = t & 63, w = t >> 6;
  __shared__ float xs[8][DD];
  __shared__ float cnt[8][34];
  __shared__ float ps[4][8][DD];
  for (int i = t; i < 8 * 34; i += 256) (&cnt[0][0])[i] = 0.f;
  __syncthreads();
  const int len = seq_lens[b];
  const int* ts = ts_g + b * LL;
  const int* lts = lts_g + b * LL;
#pragma unroll
  for (int p = 0; p < 4; ++p) {
    const int idx = p * 256 + t;
    const int jj = idx >> 7, k = idx & 127, j = j0 + jj;
    if (k <= j && j < len) {           // valid; no j==b override for labels
      const int ld = lts[j] - ts[k];   // >= 0
      atomicAdd(&cnt[jj][(ld % TU_C) / TB_C + 2], 1.f);
      atomicAdd(&cnt[jj][26 + min(ld / TU_C + 1, 7)], 1.f);
    }
  }
  __syncthreads();
  {
    float he[26], de[8];
#pragma unroll
    for (int i = 0; i < 26; ++i) he[i] = hour_emb[i * DD + t];
#pragma unroll
    for (int i = 0; i < 8; ++i)  de[i] = day_emb[i * DD + t];
    const float* fb = F + b * LL * DD + t;
    float A0 = 0.f, A1 = 0.f, A2 = 0.f, A3 = 0.f;
#pragma unroll 4
    for (int k = 0; k < j0; k += 4) {   // j0 multiple of 8
      A0 += fb[(k + 0) * DD]; A1 += fb[(k + 1) * DD];
      A2 += fb[(k + 2) * DD]; A3 += fb[(k + 3) * DD];
    }
    float gacc = (A0 + A1) + (A2 + A3);
#pragma unroll
    for (int jj = 0; jj < 8; ++jj) {
      gacc += fb[(j0 + jj) * DD];       // pooling sums ALL k<=j
      float s0 = 0.f, s1 = 0.f;
#pragma unroll
      for (int i = 0; i < 26; i += 2) {
        s0 += cnt[jj][i] * he[i]; s1 += cnt[jj][i + 1] * he[i + 1];
      }
#pragma unroll
      for (int i = 0; i < 8; i += 2) {
        s0 += cnt[jj][26 + i] * de[i]; s1 += cnt[jj][27 + i] * de[i + 1];
      }
      xs[jj][t] = (gacc + s0 + s1) / (float)(j0 + jj + 1);
    }
  }
  __syncthreads();
  // ---- Phase B: split-e GEMM (weights read once per block) ----
  const int col = c0 + 4 * l;
  float4 acc[8];
#pragma unroll
  for (int r = 0; r < 8; ++r) acc[r] = (float4){0.f, 0.f, 0.f, 0.f};
  const int e0 = 64 * w;
  for (int e = e0; e < e0 + 64; e += 4) {
    float4 xr[8];
#pragma unroll
    for (int r = 0; r < 8; ++r) xr[r] = *(const float4*)&xs[r][e];
#pragma unroll
    for (int c = 0; c < 4; ++c) {
      const float4 w4 = *(const float4*)(wtd + (e + c) * PP + col);
#pragma unroll
      for (int r = 0; r < 8; ++r) {
        const float xv = (c == 0) ? xr[r].x : (c == 1) ? xr[r].y : (c == 2) ? xr[r].z : xr[r].w;
        FMA4(acc[r], xv, w4)
      }
    }
  }
#pragma unroll
  for (int r = 0; r < 8; ++r) *(float4*)&ps[w][r][4 * l] = acc[r];
  __syncthreads();
#pragma unroll
  for (int g = 0; g < 2; ++g) {
    const int combo = g * 256 + t;
    const int r = combo >> 6, cgp = combo & 63;
    const int c4 = 4 * cgp;
    float4 o = *(const float4*)(bdec + c0 + c4);
    ADD4(o, (*(const float4*)&ps[0][r][c4]))
    ADD4(o, (*(const float4*)&ps[1][r][c4]))
    ADD4(o, (*(const float4*)&ps[2][r][c4]))
    ADD4(o, (*(const float4*)&ps[3][r][c4]))
    *(float4*)(out + (r0g + r) * PP + c0 + c4) = o;
  }
}

extern "C" void kernel_launch(void* const* d_in, const int* in_sizes, int n_in,
                              void* d_out, int out_size, void* d_ws, size_t ws_size,
                              hipStream_t stream)
{
  (void)in_sizes; (void)n_in; (void)out_size; (void)ws_size;
  const float* src      = (const float*)d_in[0];
  const float* hour_emb = (const float*)d_in[1];
  const float* day_emb  = (const float*)d_in[2];
  const float* wq  = (const float*)d_in[3];
  const float* bq  = (const float*)d_in[4];
  const float* wk  = (const float*)d_in[5];
  const float* bk  = (const float*)d_in[6];
  const float* wv  = (const float*)d_in[7];
  const float* bv  = (const float*)d_in[8];
  const float* g11 = (const float*)d_in[9];
  const float* b11 = (const float*)d_in[10];
  const float* wf1 = (const float*)d_in[11];
  const float* bf1 = (const float*)d_in[12];
  const float* wf2 = (const float*)d_in[13];
  const float* bf2 = (const float*)d_in[14];
  const float* g12 = (const float*)d_in[15];
  const float* b12 = (const float*)d_in[16];
  const float* wdec = (const float*)d_in[17];
  const float* bdec = (const float*)d_in[18];
  const int* seq_lens = (const int*)d_in[19];
  const int* ts  = (const int*)d_in[20];
  const int* lts = (const int*)d_in[21];
  float* out = (float*)d_out;
  float* ws = (float*)d_ws;
  // ws layout (floats):
  float* WT = ws;                  // 589824 (wt1 @196608, wt2 @262144, wtd @327680)
  float* Q  = ws + 589824;         // 131072
  float* KT = ws + 720896;         // 131072 (4 x [256e][128k])
  float* V  = ws + 851968;         // 131072
  float* F  = ws + 983040;         // 131072

  k_qkv2<<<256, 256, 0, stream>>>(wq, wk, wv, wf1, wf2, wdec, src,
                                  bq, bk, bv, WT, Q, KT, V);
  k_attn<<<256, 512, 0, stream>>>(Q, KT, V, src, hour_emb, day_emb, seq_lens, ts,
                                  g11, b11, WT + 196608, bf1, WT + 262144, bf2,
                                  g12, b12, F);
  k_decf<<<dim3(4, 64), 256, 0, stream>>>(F, hour_emb, day_emb, seq_lens, ts, lts,
                                          WT + 327680, bdec, out);
}

// Round 16
// 50.319 us; speedup vs baseline: 1.0576x; 1.0576x over previous
//
#include <hip/hip_runtime.h>
#include <hip/hip_bf16.h>

#define LL 128
#define DD 256
#define PP 1024
#define TU_C 86400
#define TB_C 3600
#define NEGF -4294967296.0f   // float(-2**32+1) rounds to -2^32

// NOTE: parameter names must not collide with .x/.y/.z/.w member tokens
#define FMA4(ACC_, SS_, WW_) { (ACC_).x += (SS_)*(WW_).x; (ACC_).y += (SS_)*(WW_).y; (ACC_).z += (SS_)*(WW_).z; (ACC_).w += (SS_)*(WW_).w; }
#define ADD4(ACC_, WW_) { (ACC_).x += (WW_).x; (ACC_).y += (WW_).y; (ACC_).z += (WW_).z; (ACC_).w += (WW_).w; }

__device__ __forceinline__ float wredSum(float v) {
#pragma unroll
  for (int o = 32; o; o >>= 1) v += __shfl_xor(v, o);
  return v;
}
__device__ __forceinline__ float wredMax(float v) {
#pragma unroll
  for (int o = 32; o; o >>= 1) v = fmaxf(v, __shfl_xor(v, o));
  return v;
}

// ---------------------------------------------------------------------------
// Kernel 0: transpose weights. WT: WTq 0, WTk 65536, WTv 131072, WTf1 196608,
// WTf2 262144, WTdec 327680. 32x32 tiles, 576 blocks. (proven)
// ---------------------------------------------------------------------------
__global__ __launch_bounds__(256) void k_wt(
    const float* __restrict__ wq, const float* __restrict__ wk,
    const float* __restrict__ wv, const float* __restrict__ wf1,
    const float* __restrict__ wf2, const float* __restrict__ wdec,
    float* __restrict__ wt)
{
  __shared__ float s[32][33];
  const int tile = blockIdx.x;
  const float* src; float* dst; int R, m;
  if (tile < 320) {
    const int mi = tile >> 6; m = tile & 63;
    src = (mi == 0) ? wq : (mi == 1) ? wk : (mi == 2) ? wv : (mi == 3) ? wf1 : wf2;
    dst = wt + mi * 65536; R = 256;
  } else {
    m = tile - 320; src = wdec; dst = wt + 327680; R = 1024;
  }
  const int sr = (m >> 3) * 32, sc0 = (m & 7) * 32;
  const int tx = threadIdx.x & 31, ty = threadIdx.x >> 5;
#pragma unroll
  for (int i = 0; i < 4; ++i)
    s[ty + 8 * i][tx] = src[(sr + ty + 8 * i) * 256 + sc0 + tx];
  __syncthreads();
#pragma unroll
  for (int i = 0; i < 4; ++i)
    dst[(sc0 + ty + 8 * i) * R + sr + tx] = s[tx][ty + 8 * i];
}

// ---------------------------------------------------------------------------
// Kernel 1: Q/K/V projections. grid (64,3), 256 thr = 4 waves.
// Wave w owns e-slice [64w,64w+64): each weight element loaded ONCE per
// block; 8 rows per thread via LDS broadcast; LDS combine.
// K written TRANSPOSED per batch: KT[b][e][k].
// ---------------------------------------------------------------------------
__global__ __launch_bounds__(256) void k_qkv(
    const float* __restrict__ src, const float* __restrict__ wt,
    const float* __restrict__ bq, const float* __restrict__ bk,
    const float* __restrict__ bv,
    float* __restrict__ Q, float* __restrict__ KT, float* __restrict__ V)
{
  __shared__ float xs[8][DD];
  __shared__ float ps[4][8][DD];
  const int t = threadIdx.x, l = t & 63, w = t >> 6;
  const int r0 = blockIdx.x * 8;
  const int mat = blockIdx.y;
  const float* wm = wt + mat * 65536;
  for (int i = t; i < 8 * DD; i += 256) xs[i >> 8][i & 255] = src[r0 * DD + i];
  __syncthreads();
  const int col = 4 * l;
  float4 acc[8];
#pragma unroll
  for (int r = 0; r < 8; ++r) acc[r] = (float4){0.f, 0.f, 0.f, 0.f};
  const int e0 = 64 * w;
  for (int e = e0; e < e0 + 64; e += 4) {
    float4 xr[8];
#pragma unroll
    for (int r = 0; r < 8; ++r) xr[r] = *(const float4*)&xs[r][e];
#pragma unroll
    for (int c = 0; c < 4; ++c) {
      const float4 w4 = *(const float4*)(wm + (e + c) * DD + col);
#pragma unroll
      for (int r = 0; r < 8; ++r) {
        const float xv = (c == 0) ? xr[r].x : (c == 1) ? xr[r].y : (c == 2) ? xr[r].z : xr[r].w;
        FMA4(acc[r], xv, w4)
      }
    }
  }
#pragma unroll
  for (int r = 0; r < 8; ++r) *(float4*)&ps[w][r][col] = acc[r];
  __syncthreads();
  const float* bi = (mat == 0) ? bq : (mat == 1) ? bk : bv;
#pragma unroll
  for (int g = 0; g < 2; ++g) {
    const int combo = g * 256 + t;
    const int r = combo >> 6, cgp = combo & 63;
    const int c4 = 4 * cgp;
    float4 o = *(const float4*)(bi + c4);
    ADD4(o, (*(const float4*)&ps[0][r][c4]))
    ADD4(o, (*(const float4*)&ps[1][r][c4]))
    ADD4(o, (*(const float4*)&ps[2][r][c4]))
    ADD4(o, (*(const float4*)&ps[3][r][c4]))
    const int rr = r0 + r;
    if (mat == 1) {
      const int bA = rr >> 7, kA = rr & 127;
      KT[bA * 32768 + (c4 + 0) * 128 + kA] = o.x;
      KT[bA * 32768 + (c4 + 1) * 128 + kA] = o.y;
      KT[bA * 32768 + (c4 + 2) * 128 + kA] = o.z;
      KT[bA * 32768 + (c4 + 3) * 128 + kA] = o.w;
    } else {
      float* op = (mat == 0) ? Q : V;
      *(float4*)(op + rr * DD + c4) = o;
    }
  }
}

// ---------------------------------------------------------------------------
// Kernel 2: FULLY FUSED attention + FFN. grid 256 = (b, 64 row-pairs),
// 512 thr = 8 waves. (round-11/12 proven structure)
// ---------------------------------------------------------------------------
__global__ __launch_bounds__(512) void k_attn(
    const float* __restrict__ Q, const float* __restrict__ KT,
    const float* __restrict__ Vm, const float* __restrict__ src,
    const float* __restrict__ hour_emb, const float* __restrict__ day_emb,
    const int* __restrict__ seq_lens, const int* __restrict__ ts_g,
    const float* __restrict__ g11, const float* __restrict__ b11,
    const float* __restrict__ wt1, const float* __restrict__ bf1,
    const float* __restrict__ wt2, const float* __restrict__ bf2,
    const float* __restrict__ g12, const float* __restrict__ b12,
    float* __restrict__ F)
{
  const int b = blockIdx.x >> 6;
  const int j0 = (blockIdx.x & 63) * 2;
  const int t = threadIdx.x, w = t >> 6, l = t & 63;
  const int col = 4 * l;
  __shared__ float qs[2][DD];
  __shared__ int   tsl[LL];
  __shared__ float qhd[2][34];
  __shared__ float whd[2][34];
  __shared__ float red[8];
  __shared__ float ss[2][LL];
  __shared__ float xs2[2][DD];
  __shared__ float hs2[2][DD];
  __shared__ float ps[8][2][DD];
  const int row0 = b * LL + j0;
  qs[t >> 8][t & 255] = Q[row0 * DD + t];    // 512 threads = 2x256
  if (t < LL) tsl[t] = ts_g[b * LL + t];
  if (t < 68) whd[t / 34][t % 34] = 0.f;
  __syncthreads();   // B1
  float kdot = 0.f;
  int krow = 0, kidx = 0;
  if (w < 4) {
    krow = w >> 1;
    kidx = ((w & 1) << 6) | l;
    const float* ktb = KT + b * 32768;
    float4 kd = {0.f,0.f,0.f,0.f};
#pragma unroll 8
    for (int e = 0; e < DD; e += 4) {
      const float4 q4 = *(const float4*)&qs[krow][e];
      const float* kp = ktb + e * LL + kidx;
      kd.x += q4.x * kp[0];
      kd.y += q4.y * kp[128];
      kd.z += q4.z * kp[256];
      kd.w += q4.w * kp[384];
    }
    kdot = (kd.x + kd.y) + (kd.z + kd.w);
  } else if (w < 6 && l < 34) {
    const int r = w - 4;
    const float* ep = (l < 26) ? (hour_emb + l * DD) : (day_emb + (l - 26) * DD);
    float4 ed = {0.f,0.f,0.f,0.f};
    for (int e = 0; e < DD; e += 4) {
      const float4 q4 = *(const float4*)&qs[r][e];
      const float4 e4 = *(const float4*)(ep + e);
      ed.x += q4.x * e4.x; ed.y += q4.y * e4.y;
      ed.z += q4.z * e4.z; ed.w += q4.w * e4.w;
    }
    qhd[r][l] = (ed.x + ed.y) + (ed.z + ed.w);
  }
  __syncthreads();   // B2 (qhd ready)
  const int len = seq_lens[b];
  float s = NEGF;
  int hidx = 0, didx = 0;
  if (w < 4) {
    const int jrow = j0 + krow;
    if (kidx <= jrow && jrow < len) {
      const int df = tsl[jrow] - tsl[kidx];              // >=0 (sorted, k<=j)
      hidx = (jrow == b) ? 1 : ((df % TU_C) / TB_C + 2); // faithful j==b bug
      didx = min(df / TU_C + 1, 7);
      s = (kdot + qhd[krow][hidx] + qhd[krow][26 + didx]) * 0.0625f;
    }
    const float mv = wredMax(s);
    if (l == 0) red[w] = mv;
  }
  __syncthreads();   // B3
  float p = 0.f;
  if (w < 4) {
    const float m = fmaxf(red[2 * krow], red[2 * krow + 1]);
    p = expf(s - m);                 // all-NEG row -> p=1 everywhere
    const float sv = wredSum(p);
    if (l == 0) red[4 + w] = sv;
  }
  __syncthreads();   // B4
  if (w < 4) {
    const float Z = red[4 + 2 * krow] + red[5 + 2 * krow];
    const float aw = p / Z;          // all-NEG row -> uniform 1/128
    ss[krow][kidx] = aw;
    atomicAdd(&whd[krow][hidx], aw);       // idx 0 -> zero emb row: harmless
    atomicAdd(&whd[krow][26 + didx], aw);
  }
  __syncthreads();   // B5
  // Phase 1: aw@V k-slice (16 k's per wave), both rows
  {
    float4 a0 = {0.f,0.f,0.f,0.f}, a1 = {0.f,0.f,0.f,0.f};
    const float* vb = Vm + b * LL * DD + col;
    const int k0 = 16 * w;
#pragma unroll
    for (int kk = 0; kk < 16; ++kk) {
      const int k = k0 + kk;
      const float4 v4 = *(const float4*)(vb + k * DD);
      FMA4(a0, ss[0][k], v4)
      FMA4(a1, ss[1][k], v4)
    }
    if (w == 0) {
#pragma unroll
      for (int i = 0; i < 26; ++i)
        FMA4(a0, whd[0][i], *(const float4*)(hour_emb + i * DD + col))
    } else if (w == 1) {
#pragma unroll
      for (int i = 0; i < 26; ++i)
        FMA4(a1, whd[1][i], *(const float4*)(hour_emb + i * DD + col))
    } else if (w == 2) {
#pragma unroll
      for (int i = 0; i < 8; ++i)
        FMA4(a0, whd[0][26 + i], *(const float4*)(day_emb + i * DD + col))
      const float4 s4 = *(const float4*)(src + row0 * DD + col);
      ADD4(a0, s4)
    } else if (w == 3) {
#pragma unroll
      for (int i = 0; i < 8; ++i)
        FMA4(a1, whd[1][26 + i], *(const float4*)(day_emb + i * DD + col))
      const float4 s4 = *(const float4*)(src + (row0 + 1) * DD + col);
      ADD4(a1, s4)
    }
    *(float4*)&ps[w][0][col] = a0;
    *(float4*)&ps[w][1][col] = a1;
  }
  __syncthreads();   // B6
  if (w < 2) {   // combine + LN1 (wave w = row w)
    float4 x = *(const float4*)&ps[0][w][col];
#pragma unroll
    for (int i = 1; i < 8; ++i) ADD4(x, (*(const float4*)&ps[i][w][col]))
    const float sm = wredSum(x.x + x.y + x.z + x.w);
    const float sq = wredSum(x.x*x.x + x.y*x.y + x.z*x.z + x.w*x.w);
    const float mean = sm * (1.f / DD);
    const float rstd = rsqrtf(sq * (1.f / DD) - mean * mean + 1e-5f);
    const float4 g4 = *(const float4*)(g11 + col);
    const float4 b4 = *(const float4*)(b11 + col);
    x.x = (x.x - mean) * rstd * g4.x + b4.x;
    x.y = (x.y - mean) * rstd * g4.y + b4.y;
    x.z = (x.z - mean) * rstd * g4.z + b4.z;
    x.w = (x.w - mean) * rstd * g4.w + b4.w;
    *(float4*)&xs2[w][col] = x;
  }
  __syncthreads();   // B7
  {   // FFN1 e-slice (32 e's per wave), both rows per weight read
    float4 a0 = {0.f,0.f,0.f,0.f}, a1 = {0.f,0.f,0.f,0.f};
    const int e0 = 32 * w;
#pragma unroll 8
    for (int ee = 0; ee < 32; ++ee) {
      const int e = e0 + ee;
      const float4 w4 = *(const float4*)(wt1 + e * DD + col);
      FMA4(a0, xs2[0][e], w4)
      FMA4(a1, xs2[1][e], w4)
    }
    *(float4*)&ps[w][0][col] = a0;
    *(float4*)&ps[w][1][col] = a1;
  }
  __syncthreads();   // B8
  if (w < 2) {   // combine + bias + relu
    float4 h = *(const float4*)(bf1 + col);
#pragma unroll
    for (int i = 0; i < 8; ++i) ADD4(h, (*(const float4*)&ps[i][w][col]))
    h.x = fmaxf(h.x, 0.f); h.y = fmaxf(h.y, 0.f);
    h.z = fmaxf(h.z, 0.f); h.w = fmaxf(h.w, 0.f);
    *(float4*)&hs2[w][col] = h;
  }
  __syncthreads();   // B9
  {   // FFN2 e-slice
    float4 a0 = {0.f,0.f,0.f,0.f}, a1 = {0.f,0.f,0.f,0.f};
    const int e0 = 32 * w;
#pragma unroll 8
    for (int ee = 0; ee < 32; ++ee) {
      const int e = e0 + ee;
      const float4 w4 = *(const float4*)(wt2 + e * DD + col);
      FMA4(a0, hs2[0][e], w4)
      FMA4(a1, hs2[1][e], w4)
    }
    *(float4*)&ps[w][0][col] = a0;
    *(float4*)&ps[w][1][col] = a1;
  }
  __syncthreads();   // B10
  if (w < 2) {   // combine + bias + residual + LN2 + store
    float4 o = *(const float4*)(bf2 + col);
#pragma unroll
    for (int i = 0; i < 8; ++i) ADD4(o, (*(const float4*)&ps[i][w][col]))
    const float4 xr = *(const float4*)&xs2[w][col];
    ADD4(o, xr)
    const float sm = wredSum(o.x + o.y + o.z + o.w);
    const float sq = wredSum(o.x*o.x + o.y*o.y + o.z*o.z + o.w*o.w);
    const float mean = sm * (1.f / DD);
    const float rstd = rsqrtf(sq * (1.f / DD) - mean * mean + 1e-5f);
    const float4 g4 = *(const float4*)(g12 + col);
    const float4 b4 = *(const float4*)(b12 + col);
    o.x = (o.x - mean) * rstd * g4.x + b4.x;
    o.y = (o.y - mean) * rstd * g4.y + b4.y;
    o.z = (o.z - mean) * rstd * g4.z + b4.z;
    o.w = (o.w - mean) * rstd * g4.w + b4.w;
    *(float4*)(F + (row0 + w) * DD + col) = o;
  }
}

// ---------------------------------------------------------------------------
// Kernel 3: FUSED prep + decoder GEMM. grid (4 col-tiles of 256, 64 row-tiles
// of 8) = 256 blocks, 256 thr = 4 waves.
// Phase A: GS rows in LDS (histogram + prefix over F + label-emb).
// Phase B: split-e GEMM — wave w owns e-slice [64w,64w+64); each wtd element
// loaded ONCE per block; 8 rows/thread via LDS broadcast; LDS combine.
// ---------------------------------------------------------------------------
__global__ __launch_bounds__(256) void k_decf(
    const float* __restrict__ F,
    const float* __restrict__ hour_emb, const float* __restrict__ day_emb,
    const int* __restrict__ seq_lens, const int* __restrict__ ts_g,
    const int* __restrict__ lts_g,
    const float* __restrict__ wtd, const float* __restrict__ bdec,
    float* __restrict__ out)
{
  const int c0 = blockIdx.x * 256;
  const int r0g = blockIdx.y * 8;
  const int b = r0g >> 7, j0 = r0g & 127;
  const int t = threadIdx.x, l = t & 63, w = t >> 6;
  __shared__ float xs[8][DD];
  __shared__ float cnt[8][34];
  __shared__ float ps[4][8][DD];
  for (int i = t; i < 8 * 34; i += 256) (&cnt[0][0])[i] = 0.f;
  __syncthreads();
  const int len = seq_lens[b];
  const int* ts = ts_g + b * LL;
  const int* lts = lts_g + b * LL;
#pragma unroll
  for (int p = 0; p < 4; ++p) {
    const int idx = p * 256 + t;
    const int jj = idx >> 7, k = idx & 127, j = j0 + jj;
    if (k <= j && j < len) {           // valid; no j==b override for labels
      const int ld = lts[j] - ts[k];   // >= 0
      atomicAdd(&cnt[jj][(ld % TU_C) / TB_C + 2], 1.f);
      atomicAdd(&cnt[jj][26 + min(ld / TU_C + 1, 7)], 1.f);
    }
  }
  __syncthreads();
  {
    float he[26], de[8];
#pragma unroll
    for (int i = 0; i < 26; ++i) he[i] = hour_emb[i * DD + t];
#pragma unroll
    for (int i = 0; i < 8; ++i)  de[i] = day_emb[i * DD + t];
    const float* fb = F + b * LL * DD + t;
    float A0 = 0.f, A1 = 0.f, A2 = 0.f, A3 = 0.f;
#pragma unroll 4
    for (int k = 0; k < j0; k += 4) {   // j0 multiple of 8
      A0 += fb[(k + 0) * DD]; A1 += fb[(k + 1) * DD];
      A2 += fb[(k + 2) * DD]; A3 += fb[(k + 3) * DD];
    }
    float gacc = (A0 + A1) + (A2 + A3);
#pragma unroll
    for (int jj = 0; jj < 8; ++jj) {
      gacc += fb[(j0 + jj) * DD];       // pooling sums ALL k<=j
      float s0 = 0.f, s1 = 0.f;
#pragma unroll
      for (int i = 0; i < 26; i += 2) {
        s0 += cnt[jj][i] * he[i]; s1 += cnt[jj][i + 1] * he[i + 1];
      }
#pragma unroll
      for (int i = 0; i < 8; i += 2) {
        s0 += cnt[jj][26 + i] * de[i]; s1 += cnt[jj][27 + i] * de[i + 1];
      }
      xs[jj][t] = (gacc + s0 + s1) / (float)(j0 + jj + 1);
    }
  }
  __syncthreads();
  // ---- Phase B: split-e GEMM ----
  const int col = c0 + 4 * l;
  float4 acc[8];
#pragma unroll
  for (int r = 0; r < 8; ++r) acc[r] = (float4){0.f, 0.f, 0.f, 0.f};
  const int e0 = 64 * w;
  for (int e = e0; e < e0 + 64; e += 4) {
    float4 xr[8];
#pragma unroll
    for (int r = 0; r < 8; ++r) xr[r] = *(const float4*)&xs[r][e];
#pragma unroll
    for (int c = 0; c < 4; ++c) {
      const float4 w4 = *(const float4*)(wtd + (e + c) * PP + col);
#pragma unroll
      for (int r = 0; r < 8; ++r) {
        const float xv = (c == 0) ? xr[r].x : (c == 1) ? xr[r].y : (c == 2) ? xr[r].z : xr[r].w;
        FMA4(acc[r], xv, w4)
      }
    }
  }
#pragma unroll
  for (int r = 0; r < 8; ++r) *(float4*)&ps[w][r][4 * l] = acc[r];
  __syncthreads();
#pragma unroll
  for (int g = 0; g < 2; ++g) {
    const int combo = g * 256 + t;
    const int r = combo >> 6, cgp = combo & 63;
    const int c4 = 4 * cgp;
    float4 o = *(const float4*)(bdec + c0 + c4);
    ADD4(o, (*(const float4*)&ps[0][r][c4]))
    ADD4(o, (*(const float4*)&ps[1][r][c4]))
    ADD4(o, (*(const float4*)&ps[2][r][c4]))
    ADD4(o, (*(const float4*)&ps[3][r][c4]))
    *(float4*)(out + (r0g + r) * PP + c0 + c4) = o;
  }
}

extern "C" void kernel_launch(void* const* d_in, const int* in_sizes, int n_in,
                              void* d_out, int out_size, void* d_ws, size_t ws_size,
                              hipStream_t stream)
{
  (void)in_sizes; (void)n_in; (void)out_size; (void)ws_size;
  const float* src      = (const float*)d_in[0];
  const float* hour_emb = (const float*)d_in[1];
  const float* day_emb  = (const float*)d_in[2];
  const float* wq  = (const float*)d_in[3];
  const float* bq  = (const float*)d_in[4];
  const float* wk  = (const float*)d_in[5];
  const float* bk  = (const float*)d_in[6];
  const float* wv  = (const float*)d_in[7];
  const float* bv  = (const float*)d_in[8];
  const float* g11 = (const float*)d_in[9];
  const float* b11 = (const float*)d_in[10];
  const float* wf1 = (const float*)d_in[11];
  const float* bf1 = (const float*)d_in[12];
  const float* wf2 = (const float*)d_in[13];
  const float* bf2 = (const float*)d_in[14];
  const float* g12 = (const float*)d_in[15];
  const float* b12 = (const float*)d_in[16];
  const float* wdec = (const float*)d_in[17];
  const float* bdec = (const float*)d_in[18];
  const int* seq_lens = (const int*)d_in[19];
  const int* ts  = (const int*)d_in[20];
  const int* lts = (const int*)d_in[21];
  float* out = (float*)d_out;
  float* ws = (float*)d_ws;
  // ws layout (floats):
  float* WT = ws;                  // 589824 (5x65536 + 262144)
  float* Q  = ws + 589824;         // 131072
  float* KT = ws + 720896;         // 131072 (4 x [256e][128k])
  float* V  = ws + 851968;         // 131072
  float* F  = ws + 983040;         // 131072

  k_wt  <<<576, 256, 0, stream>>>(wq, wk, wv, wf1, wf2, wdec, WT);
  k_qkv <<<dim3(64, 3), 256, 0, stream>>>(src, WT, bq, bk, bv, Q, KT, V);
  k_attn<<<256, 512, 0, stream>>>(Q, KT, V, src, hour_emb, day_emb, seq_lens, ts,
                                  g11, b11, WT + 196608, bf1, WT + 262144, bf2,
                                  g12, b12, F);
  k_decf<<<dim3(4, 64), 256, 0, stream>>>(F, hour_emb, day_emb, seq_lens, ts, lts,
                                          WT + 327680, bdec, out);
}